// Round 15
// baseline (174.108 us; speedup 1.0000x reference)
//
#include <hip/hip_runtime.h>
#include <hip/hip_bf16.h>
#include <cstdint>

// HEARConv: relation-projected edge attention + edge-softmax + weighted aggregation.
// Round 15: LDS-free score. Wave owns 32 edges x all 64 cols: A-fragments gathered DIRECTLY
// from global (4 lanes share each 128B row -> same line traffic, no duplication), W from
// L2-hot Wt per col-tile, score finished in-register (4 col-tile partial sums -> 2 heads ->
// dpp_add16). Deletes LDS tiles, 3 barriers, pack/swizzle VALU, and the combine phase.
// Pipeline: 2 memsets + fused1(pass1 || conv || Wtrans) + fused2(score || pass2) + agg.

__device__ __forceinline__ int rfl(int v) { return __builtin_amdgcn_readfirstlane(v); }

typedef __attribute__((ext_vector_type(8))) short bf16x8;
typedef __attribute__((ext_vector_type(4))) float f32x4;

#define CTR_STRIDE 16      // one counter per 64B cache line
#define RCAP 131072        // slots per relation window (mean fill 100k; overflow ~100 sigma)
#define BCAP 4864          // slots per dst-bucket window (mean 4096, sigma 64; +12 sigma)

// pack two f32 -> two bf16 (round-half-up; <=1ulp vs RNE); a = low half, b = high half
__device__ __forceinline__ uint32_t pk2(float a, float b) {
  uint32_t ua = __float_as_uint(a) + 0x8000u;
  uint32_t ub = __float_as_uint(b) + 0x8000u;
  return __builtin_amdgcn_perm(ub, ua, 0x07060302u);  // {ua.b2,ua.b3,ub.b2,ub.b3}
}

// sum across each 16-lane row via DPP row_ror (VALU-only, no LDS pipe)
__device__ __forceinline__ float dpp_add16(float x) {
  float s = x;
  int t;
  t = __builtin_amdgcn_update_dpp(0, __float_as_int(s), 0x128, 0xF, 0xF, true);
  s += __int_as_float(t);
  t = __builtin_amdgcn_update_dpp(0, __float_as_int(s), 0x124, 0xF, 0xF, true);
  s += __int_as_float(t);
  t = __builtin_amdgcn_update_dpp(0, __float_as_int(s), 0x122, 0xF, 0xF, true);
  s += __int_as_float(t);
  t = __builtin_amdgcn_update_dpp(0, __float_as_int(s), 0x121, 0xF, 0xF, true);
  s += __int_as_float(t);
  return s;
}

// per-lane mask of same-relation lanes (r is 3 bits) + rank among them. All lanes must reach.
__device__ __forceinline__ void rel_mask_rank(bool valid, int r, int lane,
                                              uint64_t& m, int& rank) {
  const uint64_t b0 = __ballot(valid && (r & 1));
  const uint64_t b1 = __ballot(valid && (r & 2));
  const uint64_t b2 = __ballot(valid && (r & 4));
  const uint64_t vv = __ballot(valid);
  m = vv;
  m &= (r & 1) ? b0 : ~b0;
  m &= (r & 2) ? b1 : ~b1;
  m &= (r & 4) ? b2 : ~b2;
  rank = (int)__popcll(m & (((uint64_t)1 << lane) - 1));
}

// ---------------- fused1: pass1 (r-sort + bucket scatter) || bf16 conv || Wtrans ---------------
__global__ __launch_bounds__(1024) void fused1_k(
    const int* __restrict__ src, const int* __restrict__ dst,
    const int* __restrict__ rt, const int* __restrict__ nid,
    int* __restrict__ cursor_r, int* __restrict__ bkt_cur,
    int* __restrict__ src_r, int* __restrict__ nid_r,
    uint2* __restrict__ recs, int E, int p1B,
    const float* __restrict__ Wsrc, const float* __restrict__ Wqual,
    ushort* __restrict__ Wt,
    const float* __restrict__ feat, const float* __restrict__ qual,
    ushort* __restrict__ feat_bf, ushort* __restrict__ qual_bf,
    long tabElems, int convB) {
  const int bx = blockIdx.x;
  if (bx >= p1B + convB) {
    // ---- W transpose to bf16 [m][r][col][k] ----
    const int gt = (bx - p1B - convB) * 1024 + threadIdx.x;   // 0..4095
    const int m = gt >> 11;
    const int r = (gt >> 8) & 7;
    const int col = (gt >> 2) & 63;
    const int k0 = (gt & 3) * 16;
    const float* W = (m ? Wqual : Wsrc) + (size_t)r * 4096;
    uint32_t o[8];
#pragma unroll
    for (int i = 0; i < 8; ++i) {
      float a = W[(k0 + 2 * i) * 64 + col];
      float b = W[(k0 + 2 * i + 1) * 64 + col];
      o[i] = pk2(a, b);
    }
    ushort* d = Wt + ((((size_t)m * 8 + r) * 64 + col) * 64 + k0);
    *(uint4*)d = make_uint4(o[0], o[1], o[2], o[3]);
    *(uint4*)(d + 8) = make_uint4(o[4], o[5], o[6], o[7]);
    return;
  }
  if (bx >= p1B) {
    // ---- bf16 table conversion: 8 elements per thread ----
    const long gt = (long)(bx - p1B) * 1024 + threadIdx.x;
    const long be = gt * 8;
    if (be < 2 * tabElems) {
      const int m = be >= tabElems;
      const long off = be - (m ? tabElems : 0);
      const float* s = (m ? qual : feat) + off;
      uint32_t o[4];
#pragma unroll
      for (int i = 0; i < 4; ++i) o[i] = pk2(s[2 * i], s[2 * i + 1]);
      *(uint4*)((m ? qual_bf : feat_bf) + off) = make_uint4(o[0], o[1], o[2], o[3]);
    }
    return;
  }
  // ---- pass1 ----
  __shared__ int wcnt[16][8];
  __shared__ int wbase[16][8];
  __shared__ int lhist[256];
  __shared__ int gbase[256];
  const int tid = threadIdx.x;
  const int wid = tid >> 6;
  const int lane = tid & 63;
  if (lane < 8) wcnt[wid][lane] = 0;
  if (tid < 256) lhist[tid] = 0;
  __syncthreads();
  const int e = bx * 1024 + tid;
  const bool valid = e < E;
  int r = 0, d = 0, b = 0, lpos = 0;
  if (valid) {
    r = rt[e];
    d = dst[e];
    b = d >> 8;
    lpos = atomicAdd(&lhist[b], 1);
  }
  uint64_t m;
  int rank;
  rel_mask_rank(valid, r, lane, m, rank);
  if (valid && rank == 0) wcnt[wid][r] = (int)__popcll(m);
  __syncthreads();
  if (tid < 8) {
    int tot = 0;
#pragma unroll
    for (int w = 0; w < 16; ++w) tot += wcnt[w][tid];
    int run = tot ? atomicAdd(&cursor_r[tid * CTR_STRIDE], tot) : 0;   // RELATIVE cursor
#pragma unroll
    for (int w = 0; w < 16; ++w) { wbase[w][tid] = run; run += wcnt[w][tid]; }
  }
  if (tid < 256) {
    const int c = lhist[tid];
    gbase[tid] = c ? atomicAdd(&bkt_cur[tid * CTR_STRIDE], c) : 0;     // RELATIVE cursor
  }
  __syncthreads();
  if (valid) {
    const int p_r = r * RCAP + wbase[wid][r] + rank;
    src_r[p_r] = src[e];
    nid_r[p_r] = nid[e];
    recs[(size_t)b * BCAP + gbase[b] + lpos] = make_uint2((uint32_t)d, (uint32_t)p_r);
  }
}

// ---------------- fused2: LDS-free score (MFMA, direct-gather fragments) || pass2 --------------
__global__ __launch_bounds__(256) void fused2_k(
    const ushort* __restrict__ feat_bf, const ushort* __restrict__ qual_bf,
    const ushort* __restrict__ Wt,
    const float* __restrict__ bsrc, const float* __restrict__ bqual,
    const float* __restrict__ attn,
    const int* __restrict__ src_r, const int* __restrict__ nid_r,
    uint2* __restrict__ rec_sa, int scoreB,
    const uint2* __restrict__ recs, const int* __restrict__ bkt_cur,
    int2* __restrict__ bc_d, int* __restrict__ perm_p, int N) {
  __shared__ __align__(16) int smem[528];          // pass2 only: 256+256+4+4 ints
  const int tid = threadIdx.x;

  if ((int)blockIdx.x >= scoreB) {
    // ---------------- pass2 (256 threads) ----------------
    int* lcnt = smem;                // 256 ints
    int* soffs = smem + 256;         // 256 ints
    int* wsum = smem + 512;          // 4 ints
    int* wb2 = smem + 516;           // 4 ints
    const int b = blockIdx.x - scoreB;
    const int dlo = b << 8;
    const int lane = tid & 63;
    const int bstart = b * BCAP;
    const int bend = bstart + bkt_cur[b * CTR_STRIDE];   // relative fill
    lcnt[tid] = 0;
    __syncthreads();
    for (int i = bstart + tid; i < bend; i += 256)
      atomicAdd(&lcnt[recs[i].x & 255u], 1);
    __syncthreads();
    int v = lcnt[tid];
    int x = v;
#pragma unroll
    for (int off = 1; off < 64; off <<= 1) {
      int y = __shfl_up(x, off);
      if (lane >= off) x += y;
    }
    if (lane == 63) wsum[tid >> 6] = x;
    __syncthreads();
    if (tid == 0) {
      int run = 0;
#pragma unroll
      for (int w = 0; w < 4; ++w) { wb2[w] = run; run += wsum[w]; }
    }
    __syncthreads();
    {
      const int st = bstart + x - v + wb2[tid >> 6];
      soffs[tid] = st;
      const int d = dlo + tid;
      if (d < N) bc_d[d] = make_int2(st, v);
      lcnt[tid] = 0;                       // reuse as rank cursors
    }
    __syncthreads();
    for (int i = bstart + tid; i < bend; i += 256) {
      const uint2 rec = recs[i];
      const int ld = (int)(rec.x & 255u);
      const int rank = atomicAdd(&lcnt[ld], 1);
      perm_p[soffs[ld] + rank] = (int)rec.y;
    }
    return;
  }

  // ---------------- score: wave = 32 edges x 64 cols, no LDS, no barriers ----------------
  const int lane = tid & 63;
  const int wid = tid >> 6;
  const int base = blockIdx.x * 128;
  const int r = blockIdx.x >> 10;          // RCAP/128 = 1024 blocks per window
  if (rfl(src_r[base]) < 0) return;        // fully-padded block (fills are contiguous)

  const int e0 = base + wid * 32;          // this wave's 32 edges
  const int erow = lane & 15;              // A-fragment row (edge within 16-tile)
  const int kg = lane >> 4;                // k-group: k = kg*8 + j (+32 for chunk 1)

  // per-lane node ids for the two 16-edge tiles (4-way replicated read, coalesced)
  const int sv0 = src_r[e0 + erow];
  const int sv1 = src_r[e0 + 16 + erow];
  const int ns0 = sv0 < 0 ? 0 : sv0;
  const int ns1 = sv1 < 0 ? 0 : sv1;
  const int nv0r = nid_r[e0 + erow];
  const int nv1r = nid_r[e0 + 16 + erow];
  const int nq0 = sv0 < 0 ? 0 : nv0r;
  const int nq1 = sv1 < 0 ? 0 : nv1r;

  // A-fragments direct from global: 16B at node*128 + kc*64 + kg*16 bytes
  const char* fb = (const char*)feat_bf;
  const char* qb = (const char*)qual_bf;
  bf16x8 aS[2][2], aQ[2][2];
  aS[0][0] = *(const bf16x8*)(fb + (size_t)ns0 * 128 + kg * 16);
  aS[0][1] = *(const bf16x8*)(fb + (size_t)ns0 * 128 + 64 + kg * 16);
  aS[1][0] = *(const bf16x8*)(fb + (size_t)ns1 * 128 + kg * 16);
  aS[1][1] = *(const bf16x8*)(fb + (size_t)ns1 * 128 + 64 + kg * 16);
  aQ[0][0] = *(const bf16x8*)(qb + (size_t)nq0 * 128 + kg * 16);
  aQ[0][1] = *(const bf16x8*)(qb + (size_t)nq0 * 128 + 64 + kg * 16);
  aQ[1][0] = *(const bf16x8*)(qb + (size_t)nq1 * 128 + kg * 16);
  aQ[1][1] = *(const bf16x8*)(qb + (size_t)nq1 * 128 + 64 + kg * 16);

  // bias/attn per col-tile (L2-broadcast scalarish loads)
  float bias[4], attnl[4];
#pragma unroll
  for (int ct = 0; ct < 4; ++ct) {
    const int col = ct * 16 + erow;
    bias[ct] = bsrc[r * 64 + col] + bqual[r * 64 + col];
    attnl[ct] = attn[r * 64 + col];
  }

  // MFMA: per col-tile load W fragments (L2-hot 128KB Wt), accumulate both edge-tiles
  f32x4 acc[2][4];
#pragma unroll
  for (int et = 0; et < 2; ++et)
#pragma unroll
    for (int ct = 0; ct < 4; ++ct) acc[et][ct] = (f32x4){0.f, 0.f, 0.f, 0.f};
#pragma unroll
  for (int ct = 0; ct < 4; ++ct) {
    const int col = ct * 16 + erow;
    const ushort* WtS = Wt + ((size_t)r * 64 + col) * 64;
    const ushort* WtQ = Wt + (((size_t)8 + r) * 64 + col) * 64;
    const bf16x8 wS0 = *(const bf16x8*)(WtS + kg * 8);
    const bf16x8 wS1 = *(const bf16x8*)(WtS + 32 + kg * 8);
    const bf16x8 wQ0 = *(const bf16x8*)(WtQ + kg * 8);
    const bf16x8 wQ1 = *(const bf16x8*)(WtQ + 32 + kg * 8);
#pragma unroll
    for (int et = 0; et < 2; ++et) {
      acc[et][ct] = __builtin_amdgcn_mfma_f32_16x16x32_bf16(aS[et][0], wS0, acc[et][ct], 0, 0, 0);
      acc[et][ct] = __builtin_amdgcn_mfma_f32_16x16x32_bf16(aS[et][1], wS1, acc[et][ct], 0, 0, 0);
      acc[et][ct] = __builtin_amdgcn_mfma_f32_16x16x32_bf16(aQ[et][0], wQ0, acc[et][ct], 0, 0, 0);
      acc[et][ct] = __builtin_amdgcn_mfma_f32_16x16x32_bf16(aQ[et][1], wQ1, acc[et][ct], 0, 0, 0);
    }
  }

  // epilogue: leaky + attn-dot in-register; D row=(kg)*4+j (edge within tile), col=lane&15.
  // cols 0..31 (ct 0,1) -> head0; 32..63 (ct 2,3) -> head1. dpp_add16 reduces over erow.
#pragma unroll
  for (int et = 0; et < 2; ++et) {
#pragma unroll
    for (int j = 0; j < 4; ++j) {
      float s0 = 0.f, s1 = 0.f;
#pragma unroll
      for (int ct = 0; ct < 4; ++ct) {
        float v = acc[et][ct][j] + bias[ct];
        v = v > 0.f ? v : 0.2f * v;           // leaky_relu
        if (ct < 2) s0 = fmaf(v, attnl[ct], s0);
        else        s1 = fmaf(v, attnl[ct], s1);
      }
      s0 = dpp_add16(s0);
      s1 = dpp_add16(s1);
      if (erow == 0) {                        // lanes 0,16,32,48: one edge per k-group
        const int ei = et * 16 + kg * 4 + j;
        rec_sa[e0 + ei] = make_uint2(pk2(s0, s1), (uint32_t)src_r[e0 + ei]);
      }
    }
  }
}

// ---------------- aggregation: persistent, FOUR dst nodes per wave (16-lane groups) ------------
__global__ __launch_bounds__(256) void agg_k(
    const ushort* __restrict__ feat_bf, const uint2* __restrict__ rec_sa,
    const int* __restrict__ perm_p, const int2* __restrict__ bc_d,
    float* __restrict__ out, int N, int nquads) {
  const int lane = threadIdx.x & 63;
  const int wid = threadIdx.x >> 6;
  const int g = lane >> 4;
  const int gl = lane & 15;
  const int gbase = g << 4;

  for (int q = blockIdx.x * 4 + wid; q < nquads; q += 2048 * 4) {
    const int n = q * 4 + g;
    if (n >= N) continue;                // no barriers below: safe divergence
    const int2 bc = bc_d[n];
    const int beg = bc.x;
    const int cnt = bc.y;
    float A0[4] = {0.f, 0.f, 0.f, 0.f};
    float A1[4] = {0.f, 0.f, 0.f, 0.f};
    float d0 = 0.f, d1 = 0.f;

    if (cnt > 0 && cnt <= 32) {
      // ---- 2 register rounds of 8B edge records ----
      const bool v0 = gl < cnt;
      const bool v1 = gl + 16 < cnt;
      float sx0 = -3.4e38f, sy0 = -3.4e38f, sx1 = -3.4e38f, sy1 = -3.4e38f;
      int sl0 = 0, sl1 = 0;
      if (v0) {
        const uint2 rec = rec_sa[perm_p[beg + gl]];
        sx0 = __uint_as_float(rec.x << 16);
        sy0 = __uint_as_float(rec.x & 0xffff0000u);
        sl0 = (int)rec.y;
      }
      if (v1) {
        const uint2 rec = rec_sa[perm_p[beg + 16 + gl]];
        sx1 = __uint_as_float(rec.x << 16);
        sy1 = __uint_as_float(rec.x & 0xffff0000u);
        sl1 = (int)rec.y;
      }
      float m0 = fmaxf(sx0, sx1), m1 = fmaxf(sy0, sy1);
#pragma unroll
      for (int off = 8; off; off >>= 1) {
        m0 = fmaxf(m0, __shfl_xor(m0, off));
        m1 = fmaxf(m1, __shfl_xor(m1, off));
      }
      const float z0a = v0 ? __expf(sx0 - m0) : 0.f;
      const float z1a = v0 ? __expf(sy0 - m1) : 0.f;
      const float z0b = v1 ? __expf(sx1 - m0) : 0.f;
      const float z1b = v1 ? __expf(sy1 - m1) : 0.f;
      d0 = z0a + z0b;
      d1 = z1a + z1b;
#pragma unroll 4
      for (int k = 0; k < cnt; ++k) {
        const int srcl = gbase + (k & 15);
        const int hi = k >> 4;             // uniform within group
        const int ss = __shfl(hi ? sl1 : sl0, srcl);
        const float w0 = __shfl(hi ? z0b : z0a, srcl);
        const float w1 = __shfl(hi ? z1b : z1a, srcl);
        const uint2 fv = *(const uint2*)(feat_bf + (size_t)ss * 64 + (gl << 2));
        const float f0 = __uint_as_float(fv.x << 16);
        const float f1 = __uint_as_float(fv.x & 0xffff0000u);
        const float f2 = __uint_as_float(fv.y << 16);
        const float f3 = __uint_as_float(fv.y & 0xffff0000u);
        A0[0] = fmaf(f0, w0, A0[0]); A0[1] = fmaf(f1, w0, A0[1]);
        A0[2] = fmaf(f2, w0, A0[2]); A0[3] = fmaf(f3, w0, A0[3]);
        A1[0] = fmaf(f0, w1, A1[0]); A1[1] = fmaf(f1, w1, A1[1]);
        A1[2] = fmaf(f2, w1, A1[2]); A1[3] = fmaf(f3, w1, A1[3]);
      }
    } else if (cnt > 32) {
      // ---- general path: strided rounds of 16 ----
      float m0 = -3.4e38f, m1 = -3.4e38f;
      for (int i = gl; i < cnt; i += 16) {
        const uint2 rec = rec_sa[perm_p[beg + i]];
        m0 = fmaxf(m0, __uint_as_float(rec.x << 16));
        m1 = fmaxf(m1, __uint_as_float(rec.x & 0xffff0000u));
      }
#pragma unroll
      for (int off = 8; off; off >>= 1) {
        m0 = fmaxf(m0, __shfl_xor(m0, off));
        m1 = fmaxf(m1, __shfl_xor(m1, off));
      }
      for (int c0 = 0; c0 < cnt; c0 += 16) {
        const int i = c0 + gl;
        const bool val = i < cnt;
        int sl = 0;
        float z0 = 0.f, z1 = 0.f;
        if (val) {
          const uint2 rec = rec_sa[perm_p[beg + i]];
          z0 = __expf(__uint_as_float(rec.x << 16) - m0);
          z1 = __expf(__uint_as_float(rec.x & 0xffff0000u) - m1);
          sl = (int)rec.y;
        }
        d0 += z0;
        d1 += z1;
        const int kmax = min(16, cnt - c0);
#pragma unroll 4
        for (int k = 0; k < kmax; ++k) {
          const int srcl = gbase + k;
          const int ss = __shfl(sl, srcl);
          const float w0 = __shfl(z0, srcl);
          const float w1 = __shfl(z1, srcl);
          const uint2 fv = *(const uint2*)(feat_bf + (size_t)ss * 64 + (gl << 2));
          const float f0 = __uint_as_float(fv.x << 16);
          const float f1 = __uint_as_float(fv.x & 0xffff0000u);
          const float f2 = __uint_as_float(fv.y << 16);
          const float f3 = __uint_as_float(fv.y & 0xffff0000u);
          A0[0] = fmaf(f0, w0, A0[0]); A0[1] = fmaf(f1, w0, A0[1]);
          A0[2] = fmaf(f2, w0, A0[2]); A0[3] = fmaf(f3, w0, A0[3]);
          A1[0] = fmaf(f0, w1, A1[0]); A1[1] = fmaf(f1, w1, A1[1]);
          A1[2] = fmaf(f2, w1, A1[2]); A1[3] = fmaf(f3, w1, A1[3]);
        }
      }
    }
    // group-sum denominators + write 4 elems/head per lane (two coalesced 16B stores)
#pragma unroll
    for (int off = 8; off; off >>= 1) {
      d0 += __shfl_xor(d0, off);
      d1 += __shfl_xor(d1, off);
    }
    const float r0 = (cnt > 0) ? 1.f / d0 : 0.f;
    const float r1 = (cnt > 0) ? 1.f / d1 : 0.f;
    float4 s0 = make_float4(A0[0] * r0, A0[1] * r0, A0[2] * r0, A0[3] * r0);
    float4 s1 = make_float4(A1[0] * r1, A1[1] * r1, A1[2] * r1, A1[3] * r1);
    *(float4*)(out + (size_t)n * 128 + (gl << 2)) = s0;
    *(float4*)(out + (size_t)n * 128 + 64 + (gl << 2)) = s1;
  }
}

extern "C" void kernel_launch(void* const* d_in, const int* in_sizes, int n_in,
                              void* d_out, int out_size, void* d_ws, size_t ws_size,
                              hipStream_t stream) {
  const float* feat  = (const float*)d_in[0];
  const float* Wsrc  = (const float*)d_in[1];
  const float* bsrc  = (const float*)d_in[2];
  const float* qual  = (const float*)d_in[3];
  const float* Wqual = (const float*)d_in[4];
  const float* bqual = (const float*)d_in[5];
  const float* attn  = (const float*)d_in[6];
  const int* src = (const int*)d_in[7];
  const int* dst = (const int*)d_in[8];
  const int* rt  = (const int*)d_in[9];
  const int* nid = (const int*)d_in[10];
  float* out = (float*)d_out;

  const int N = in_sizes[0] / 64;
  const int E = in_sizes[7];
  const long tabElems = (long)N * 64;
  const int NBKT = (N + 255) / 256;
  const size_t RSLOTS = (size_t)8 * RCAP;

  char* p = (char*)d_ws;
  int* cursor_r = (int*)p;      p += 8 * CTR_STRIDE * 4;
  int* bkt_cur = (int*)p;       p += (size_t)NBKT * CTR_STRIDE * 4;   // contiguous w/ cursor_r
  int2* bc_d = (int2*)p;        p += (size_t)N * 8;
  int* src_r = (int*)p;         p += RSLOTS * 4;
  int* nid_r = (int*)p;         p += RSLOTS * 4;
  uint2* recs = (uint2*)p;      p += (size_t)NBKT * BCAP * 8;
  int* perm_p = (int*)p;        p += (size_t)NBKT * BCAP * 4;
  ushort* Wt = (ushort*)p;      p += 2 * 8 * 64 * 64 * 2;  // 128 KB bf16
  ushort* feat_bf = (ushort*)p; p += (size_t)tabElems * 2;
  ushort* qual_bf = (ushort*)p; p += (size_t)tabElems * 2;
  uint2* rec_sa = (uint2*)p;    p += RSLOTS * 8;
  if ((size_t)(p - (char*)d_ws) > ws_size) return;   // workspace too small: bail visibly

  hipMemsetAsync(cursor_r, 0, (size_t)(8 + NBKT) * CTR_STRIDE * 4, stream);  // relative cursors
  hipMemsetAsync(src_r, 0xFF, RSLOTS * 4, stream);   // -1 sentinels for window padding

  const int p1B = (E + 1023) / 1024;
  const int convB = (int)((2 * tabElems / 8 + 1023) / 1024);
  fused1_k<<<p1B + convB + 4, 1024, 0, stream>>>(src, dst, rt, nid, cursor_r, bkt_cur,
                                                 src_r, nid_r, recs, E, p1B,
                                                 Wsrc, Wqual, Wt,
                                                 feat, qual, feat_bf, qual_bf,
                                                 tabElems, convB);
  const int scoreB = (int)(RSLOTS / 128);
  fused2_k<<<scoreB + NBKT, 256, 0, stream>>>(feat_bf, qual_bf, Wt, bsrc, bqual, attn,
                                              src_r, nid_r, rec_sa, scoreB,
                                              recs, bkt_cur, bc_d, perm_p, N);
  const int nquads = (N + 3) / 4;
  const int aggB = min(2048, (nquads + 3) / 4);
  agg_k<<<aggB, 256, 0, stream>>>(feat_bf, rec_sa, perm_p, bc_d, out, N, nquads);
}

// Round 16
// 129.819 us; speedup vs baseline: 1.3412x; 1.3412x over previous
//
#include <hip/hip_runtime.h>
#include <hip/hip_bf16.h>
#include <cstdint>

// HEARConv: relation-projected edge attention + edge-softmax + weighted aggregation.
// Round 16: REVERT to Round-14 structure (LDS-staged score). R15's LDS-free direct-gather
// score regressed 2x: per-lane 16B random gathers fan each wave-load out to ~32 lines with
// no latency decoupling; the LDS stage's 64B-contiguous per-thread loads + barrier pipeline
// were the coalescing/decoupling mechanism, not overhead.
// Pipeline: 2 memsets + fused1(pass1 || conv || Wtrans) + fused2(score || pass2) + agg.

__device__ __forceinline__ int rfl(int v) { return __builtin_amdgcn_readfirstlane(v); }

typedef __attribute__((ext_vector_type(8))) short bf16x8;
typedef __attribute__((ext_vector_type(4))) float f32x4;

#define CTR_STRIDE 16      // one counter per 64B cache line
#define RCAP 131072        // slots per relation window (mean fill 100k; overflow ~100 sigma)
#define BCAP 4864          // slots per dst-bucket window (mean 4096, sigma 64; +12 sigma)

// pack two f32 -> two bf16 (round-half-up; <=1ulp vs RNE); a = low half, b = high half
__device__ __forceinline__ uint32_t pk2(float a, float b) {
  uint32_t ua = __float_as_uint(a) + 0x8000u;
  uint32_t ub = __float_as_uint(b) + 0x8000u;
  return __builtin_amdgcn_perm(ub, ua, 0x07060302u);  // {ua.b2,ua.b3,ub.b2,ub.b3}
}

// sum across each 16-lane row via DPP row_ror (VALU-only, no LDS pipe)
__device__ __forceinline__ float dpp_add16(float x) {
  float s = x;
  int t;
  t = __builtin_amdgcn_update_dpp(0, __float_as_int(s), 0x128, 0xF, 0xF, true);
  s += __int_as_float(t);
  t = __builtin_amdgcn_update_dpp(0, __float_as_int(s), 0x124, 0xF, 0xF, true);
  s += __int_as_float(t);
  t = __builtin_amdgcn_update_dpp(0, __float_as_int(s), 0x122, 0xF, 0xF, true);
  s += __int_as_float(t);
  t = __builtin_amdgcn_update_dpp(0, __float_as_int(s), 0x121, 0xF, 0xF, true);
  s += __int_as_float(t);
  return s;
}

// per-lane mask of same-relation lanes (r is 3 bits) + rank among them. All lanes must reach.
__device__ __forceinline__ void rel_mask_rank(bool valid, int r, int lane,
                                              uint64_t& m, int& rank) {
  const uint64_t b0 = __ballot(valid && (r & 1));
  const uint64_t b1 = __ballot(valid && (r & 2));
  const uint64_t b2 = __ballot(valid && (r & 4));
  const uint64_t vv = __ballot(valid);
  m = vv;
  m &= (r & 1) ? b0 : ~b0;
  m &= (r & 2) ? b1 : ~b1;
  m &= (r & 4) ? b2 : ~b2;
  rank = (int)__popcll(m & (((uint64_t)1 << lane) - 1));
}

// ---------------- fused1: pass1 (r-sort + bucket scatter) || bf16 conv || Wtrans ---------------
__global__ __launch_bounds__(1024) void fused1_k(
    const int* __restrict__ src, const int* __restrict__ dst,
    const int* __restrict__ rt, const int* __restrict__ nid,
    int* __restrict__ cursor_r, int* __restrict__ bkt_cur,
    int* __restrict__ src_r, int* __restrict__ nid_r,
    uint2* __restrict__ recs, int E, int p1B,
    const float* __restrict__ Wsrc, const float* __restrict__ Wqual,
    ushort* __restrict__ Wt,
    const float* __restrict__ feat, const float* __restrict__ qual,
    ushort* __restrict__ feat_bf, ushort* __restrict__ qual_bf,
    long tabElems, int convB) {
  const int bx = blockIdx.x;
  if (bx >= p1B + convB) {
    // ---- W transpose to bf16 [m][r][col][k] ----
    const int gt = (bx - p1B - convB) * 1024 + threadIdx.x;   // 0..4095
    const int m = gt >> 11;
    const int r = (gt >> 8) & 7;
    const int col = (gt >> 2) & 63;
    const int k0 = (gt & 3) * 16;
    const float* W = (m ? Wqual : Wsrc) + (size_t)r * 4096;
    uint32_t o[8];
#pragma unroll
    for (int i = 0; i < 8; ++i) {
      float a = W[(k0 + 2 * i) * 64 + col];
      float b = W[(k0 + 2 * i + 1) * 64 + col];
      o[i] = pk2(a, b);
    }
    ushort* d = Wt + ((((size_t)m * 8 + r) * 64 + col) * 64 + k0);
    *(uint4*)d = make_uint4(o[0], o[1], o[2], o[3]);
    *(uint4*)(d + 8) = make_uint4(o[4], o[5], o[6], o[7]);
    return;
  }
  if (bx >= p1B) {
    // ---- bf16 table conversion: 8 elements per thread ----
    const long gt = (long)(bx - p1B) * 1024 + threadIdx.x;
    const long be = gt * 8;
    if (be < 2 * tabElems) {
      const int m = be >= tabElems;
      const long off = be - (m ? tabElems : 0);
      const float* s = (m ? qual : feat) + off;
      uint32_t o[4];
#pragma unroll
      for (int i = 0; i < 4; ++i) o[i] = pk2(s[2 * i], s[2 * i + 1]);
      *(uint4*)((m ? qual_bf : feat_bf) + off) = make_uint4(o[0], o[1], o[2], o[3]);
    }
    return;
  }
  // ---- pass1 ----
  __shared__ int wcnt[16][8];
  __shared__ int wbase[16][8];
  __shared__ int lhist[256];
  __shared__ int gbase[256];
  const int tid = threadIdx.x;
  const int wid = tid >> 6;
  const int lane = tid & 63;
  if (lane < 8) wcnt[wid][lane] = 0;
  if (tid < 256) lhist[tid] = 0;
  __syncthreads();
  const int e = bx * 1024 + tid;
  const bool valid = e < E;
  int r = 0, d = 0, b = 0, lpos = 0;
  if (valid) {
    r = rt[e];
    d = dst[e];
    b = d >> 8;
    lpos = atomicAdd(&lhist[b], 1);
  }
  uint64_t m;
  int rank;
  rel_mask_rank(valid, r, lane, m, rank);
  if (valid && rank == 0) wcnt[wid][r] = (int)__popcll(m);
  __syncthreads();
  if (tid < 8) {
    int tot = 0;
#pragma unroll
    for (int w = 0; w < 16; ++w) tot += wcnt[w][tid];
    int run = tot ? atomicAdd(&cursor_r[tid * CTR_STRIDE], tot) : 0;   // RELATIVE cursor
#pragma unroll
    for (int w = 0; w < 16; ++w) { wbase[w][tid] = run; run += wcnt[w][tid]; }
  }
  if (tid < 256) {
    const int c = lhist[tid];
    gbase[tid] = c ? atomicAdd(&bkt_cur[tid * CTR_STRIDE], c) : 0;     // RELATIVE cursor
  }
  __syncthreads();
  if (valid) {
    const int p_r = r * RCAP + wbase[wid][r] + rank;
    src_r[p_r] = src[e];
    nid_r[p_r] = nid[e];
    recs[(size_t)b * BCAP + gbase[b] + lpos] = make_uint2((uint32_t)d, (uint32_t)p_r);
  }
}

// ---------------- fused2: score (MFMA windows) || pass2 (per-bucket dst offsets + perm) --------
__global__ __launch_bounds__(256, 8) void fused2_k(
    const ushort* __restrict__ feat_bf, const ushort* __restrict__ qual_bf,
    const ushort* __restrict__ Wt,
    const float* __restrict__ bsrc, const float* __restrict__ bqual,
    const float* __restrict__ attn,
    const int* __restrict__ src_r, const int* __restrict__ nid_r,
    uint2* __restrict__ rec_sa, int scoreB,
    const uint2* __restrict__ recs, const int* __restrict__ bkt_cur,
    int2* __restrict__ bc_d, int* __restrict__ perm_p, int N) {
  __shared__ __align__(16) char smem[18432];      // overlaid: score 18KB / pass2 2.1KB
  const int tid = threadIdx.x;

  if ((int)blockIdx.x >= scoreB) {
    // ---------------- pass2 (256 threads) ----------------
    int* lcnt = (int*)smem;                // 256 ints
    int* soffs = (int*)(smem + 1024);      // 256 ints
    int* wsum = (int*)(smem + 2048);       // 4 ints
    int* wb2 = (int*)(smem + 2064);        // 4 ints
    const int b = blockIdx.x - scoreB;
    const int dlo = b << 8;
    const int lane = tid & 63;
    const int bstart = b * BCAP;
    const int bend = bstart + bkt_cur[b * CTR_STRIDE];   // relative fill
    lcnt[tid] = 0;
    __syncthreads();
    for (int i = bstart + tid; i < bend; i += 256)
      atomicAdd(&lcnt[recs[i].x & 255u], 1);
    __syncthreads();
    int v = lcnt[tid];
    int x = v;
#pragma unroll
    for (int off = 1; off < 64; off <<= 1) {
      int y = __shfl_up(x, off);
      if (lane >= off) x += y;
    }
    if (lane == 63) wsum[tid >> 6] = x;
    __syncthreads();
    if (tid == 0) {
      int run = 0;
#pragma unroll
      for (int w = 0; w < 4; ++w) { wb2[w] = run; run += wsum[w]; }
    }
    __syncthreads();
    {
      const int st = bstart + x - v + wb2[tid >> 6];
      soffs[tid] = st;
      const int d = dlo + tid;
      if (d < N) bc_d[d] = make_int2(st, v);
      lcnt[tid] = 0;                       // reuse as rank cursors
    }
    __syncthreads();
    for (int i = bstart + tid; i < bend; i += 256) {
      const uint2 rec = recs[i];
      const int ld = (int)(rec.x & 255u);
      const int rank = atomicAdd(&lcnt[ld], 1);
      perm_p[soffs[ld] + rank] = (int)rec.y;
    }
    return;
  }

  // ---------------- score ----------------
  ushort* lT0 = (ushort*)smem;             // [64][64] feat tile, 8KB
  ushort* lT1 = (ushort*)(smem + 8192);    // [64][64] qual tile, 8KB
  float* comb = (float*)(smem + 16384);    // [4][128], 2KB
  const int lane = tid & 63;
  const int wid = tid >> 6;
  const int base = blockIdx.x * 128;
  const int r = blockIdx.x >> 10;          // RCAP/128 = 1024 blocks per window
  if (rfl(src_r[base]) < 0) return;        // fully-padded block

  // B fragments: col = wid*16 + lane&15, k = (lane>>4)*8 + j  (coalesced 16B from Wt)
  const int col = wid * 16 + (lane & 15);
  const int kb = (lane >> 4) * 8;
  const ushort* WtS = Wt + ((size_t)r * 64 + col) * 64;
  const ushort* WtQ = Wt + (((size_t)8 + r) * 64 + col) * 64;
  const bf16x8 wS0 = *(const bf16x8*)(WtS + kb);
  const bf16x8 wS1 = *(const bf16x8*)(WtS + 32 + kb);
  const bf16x8 wQ0 = *(const bf16x8*)(WtQ + kb);
  const bf16x8 wQ1 = *(const bf16x8*)(WtQ + 32 + kb);
  const float bias_l = bsrc[r * 64 + col] + bqual[r * 64 + col];
  const float attn_l = attn[r * 64 + col];

  for (int sb = 0; sb < 2; ++sb) {
    // ---- stage 64 edges: straight 16B bf16 copies (half a 128B row per thread) ----
    {
      const int m = tid >> 7;          // 0 = feat, 1 = qual
      const int es = (tid >> 1) & 63;  // edge slot in sub-batch
      const int hf = tid & 1;          // row half
      const int gs = base + sb * 64 + es;
      const int sv = src_r[gs];
      char* dp = (char*)((m ? lT1 : lT0) + es * 64);
      const int swz = (es & 7) << 4;
      if (sv >= 0) {
        const int node = m ? nid_r[gs] : sv;
        const char* gp = (const char*)(m ? qual_bf : feat_bf) + (size_t)node * 128 + hf * 64;
#pragma unroll
        for (int c = 0; c < 4; ++c)
          *(uint4*)(dp + ((hf * 64 + c * 16) ^ swz)) = *(const uint4*)(gp + c * 16);
      } else {
        uint4 z = make_uint4(0, 0, 0, 0);
#pragma unroll
        for (int c = 0; c < 4; ++c) *(uint4*)(dp + ((hf * 64 + c * 16) ^ swz)) = z;
      }
    }
    __syncthreads();

    // ---- 4 edge-tiles of 16: feat and qual accumulate into the SAME acc ----
#pragma unroll
    for (int et = 0; et < 4; ++et) {
      const int row = et * 16 + (lane & 15);
      const int rb = row * 128;
      const int swz = (row & 7) << 4;
      const int k0 = (lane >> 4) * 16;
      bf16x8 aS0 = *(const bf16x8*)((const char*)lT0 + rb + (k0 ^ swz));
      bf16x8 aS1 = *(const bf16x8*)((const char*)lT0 + rb + ((k0 + 64) ^ swz));
      bf16x8 aQ0 = *(const bf16x8*)((const char*)lT1 + rb + (k0 ^ swz));
      bf16x8 aQ1 = *(const bf16x8*)((const char*)lT1 + rb + ((k0 + 64) ^ swz));
      f32x4 acc = {0.f, 0.f, 0.f, 0.f};
      acc = __builtin_amdgcn_mfma_f32_16x16x32_bf16(aS0, wS0, acc, 0, 0, 0);
      acc = __builtin_amdgcn_mfma_f32_16x16x32_bf16(aS1, wS1, acc, 0, 0, 0);
      acc = __builtin_amdgcn_mfma_f32_16x16x32_bf16(aQ0, wQ0, acc, 0, 0, 0);
      acc = __builtin_amdgcn_mfma_f32_16x16x32_bf16(aQ1, wQ1, acc, 0, 0, 0);

      // epilogue: D row=(lane>>4)*4+j (edge), col=lane&15; DPP 16-lane reduce (VALU-only)
      float p0, p1, p2, p3;
#pragma unroll
      for (int j = 0; j < 4; ++j) {
        float v = acc[j] + bias_l;
        v = v > 0.f ? v : 0.2f * v;           // leaky_relu
        float s = dpp_add16(v * attn_l);
        if (j == 0) p0 = s; else if (j == 1) p1 = s; else if (j == 2) p2 = s; else p3 = s;
      }
      const int sub = lane & 15;
      if (sub < 4) {
        float v = sub == 0 ? p0 : sub == 1 ? p1 : sub == 2 ? p2 : p3;
        comb[wid * 128 + sb * 64 + et * 16 + (lane >> 4) * 4 + sub] = v;
      }
    }
    __syncthreads();
  }

  // ---- combine waves -> coalesced 8B record {pk2(s0,s1), src} in r-sorted order ----
  if (tid < 128) {
    const int gs = base + tid;
    rec_sa[gs] = make_uint2(pk2(comb[0 * 128 + tid] + comb[1 * 128 + tid],
                                comb[2 * 128 + tid] + comb[3 * 128 + tid]),
                            (uint32_t)src_r[gs]);
  }
}

// ---------------- aggregation: persistent, FOUR dst nodes per wave (16-lane groups) ------------
__global__ __launch_bounds__(256) void agg_k(
    const ushort* __restrict__ feat_bf, const uint2* __restrict__ rec_sa,
    const int* __restrict__ perm_p, const int2* __restrict__ bc_d,
    float* __restrict__ out, int N, int nquads) {
  const int lane = threadIdx.x & 63;
  const int wid = threadIdx.x >> 6;
  const int g = lane >> 4;
  const int gl = lane & 15;
  const int gbase = g << 4;

  for (int q = blockIdx.x * 4 + wid; q < nquads; q += 2048 * 4) {
    const int n = q * 4 + g;
    if (n >= N) continue;                // no barriers below: safe divergence
    const int2 bc = bc_d[n];
    const int beg = bc.x;
    const int cnt = bc.y;
    float A0[4] = {0.f, 0.f, 0.f, 0.f};
    float A1[4] = {0.f, 0.f, 0.f, 0.f};
    float d0 = 0.f, d1 = 0.f;

    if (cnt > 0 && cnt <= 32) {
      // ---- 2 register rounds of 8B edge records ----
      const bool v0 = gl < cnt;
      const bool v1 = gl + 16 < cnt;
      float sx0 = -3.4e38f, sy0 = -3.4e38f, sx1 = -3.4e38f, sy1 = -3.4e38f;
      int sl0 = 0, sl1 = 0;
      if (v0) {
        const uint2 rec = rec_sa[perm_p[beg + gl]];
        sx0 = __uint_as_float(rec.x << 16);
        sy0 = __uint_as_float(rec.x & 0xffff0000u);
        sl0 = (int)rec.y;
      }
      if (v1) {
        const uint2 rec = rec_sa[perm_p[beg + 16 + gl]];
        sx1 = __uint_as_float(rec.x << 16);
        sy1 = __uint_as_float(rec.x & 0xffff0000u);
        sl1 = (int)rec.y;
      }
      float m0 = fmaxf(sx0, sx1), m1 = fmaxf(sy0, sy1);
#pragma unroll
      for (int off = 8; off; off >>= 1) {
        m0 = fmaxf(m0, __shfl_xor(m0, off));
        m1 = fmaxf(m1, __shfl_xor(m1, off));
      }
      const float z0a = v0 ? __expf(sx0 - m0) : 0.f;
      const float z1a = v0 ? __expf(sy0 - m1) : 0.f;
      const float z0b = v1 ? __expf(sx1 - m0) : 0.f;
      const float z1b = v1 ? __expf(sy1 - m1) : 0.f;
      d0 = z0a + z0b;
      d1 = z1a + z1b;
#pragma unroll 4
      for (int k = 0; k < cnt; ++k) {
        const int srcl = gbase + (k & 15);
        const int hi = k >> 4;             // uniform within group
        const int ss = __shfl(hi ? sl1 : sl0, srcl);
        const float w0 = __shfl(hi ? z0b : z0a, srcl);
        const float w1 = __shfl(hi ? z1b : z1a, srcl);
        const uint2 fv = *(const uint2*)(feat_bf + (size_t)ss * 64 + (gl << 2));
        const float f0 = __uint_as_float(fv.x << 16);
        const float f1 = __uint_as_float(fv.x & 0xffff0000u);
        const float f2 = __uint_as_float(fv.y << 16);
        const float f3 = __uint_as_float(fv.y & 0xffff0000u);
        A0[0] = fmaf(f0, w0, A0[0]); A0[1] = fmaf(f1, w0, A0[1]);
        A0[2] = fmaf(f2, w0, A0[2]); A0[3] = fmaf(f3, w0, A0[3]);
        A1[0] = fmaf(f0, w1, A1[0]); A1[1] = fmaf(f1, w1, A1[1]);
        A1[2] = fmaf(f2, w1, A1[2]); A1[3] = fmaf(f3, w1, A1[3]);
      }
    } else if (cnt > 32) {
      // ---- general path: strided rounds of 16 ----
      float m0 = -3.4e38f, m1 = -3.4e38f;
      for (int i = gl; i < cnt; i += 16) {
        const uint2 rec = rec_sa[perm_p[beg + i]];
        m0 = fmaxf(m0, __uint_as_float(rec.x << 16));
        m1 = fmaxf(m1, __uint_as_float(rec.x & 0xffff0000u));
      }
#pragma unroll
      for (int off = 8; off; off >>= 1) {
        m0 = fmaxf(m0, __shfl_xor(m0, off));
        m1 = fmaxf(m1, __shfl_xor(m1, off));
      }
      for (int c0 = 0; c0 < cnt; c0 += 16) {
        const int i = c0 + gl;
        const bool val = i < cnt;
        int sl = 0;
        float z0 = 0.f, z1 = 0.f;
        if (val) {
          const uint2 rec = rec_sa[perm_p[beg + i]];
          z0 = __expf(__uint_as_float(rec.x << 16) - m0);
          z1 = __expf(__uint_as_float(rec.x & 0xffff0000u) - m1);
          sl = (int)rec.y;
        }
        d0 += z0;
        d1 += z1;
        const int kmax = min(16, cnt - c0);
#pragma unroll 4
        for (int k = 0; k < kmax; ++k) {
          const int srcl = gbase + k;
          const int ss = __shfl(sl, srcl);
          const float w0 = __shfl(z0, srcl);
          const float w1 = __shfl(z1, srcl);
          const uint2 fv = *(const uint2*)(feat_bf + (size_t)ss * 64 + (gl << 2));
          const float f0 = __uint_as_float(fv.x << 16);
          const float f1 = __uint_as_float(fv.x & 0xffff0000u);
          const float f2 = __uint_as_float(fv.y << 16);
          const float f3 = __uint_as_float(fv.y & 0xffff0000u);
          A0[0] = fmaf(f0, w0, A0[0]); A0[1] = fmaf(f1, w0, A0[1]);
          A0[2] = fmaf(f2, w0, A0[2]); A0[3] = fmaf(f3, w0, A0[3]);
          A1[0] = fmaf(f0, w1, A1[0]); A1[1] = fmaf(f1, w1, A1[1]);
          A1[2] = fmaf(f2, w1, A1[2]); A1[3] = fmaf(f3, w1, A1[3]);
        }
      }
    }
    // group-sum denominators + write 4 elems/head per lane (two coalesced 16B stores)
#pragma unroll
    for (int off = 8; off; off >>= 1) {
      d0 += __shfl_xor(d0, off);
      d1 += __shfl_xor(d1, off);
    }
    const float r0 = (cnt > 0) ? 1.f / d0 : 0.f;
    const float r1 = (cnt > 0) ? 1.f / d1 : 0.f;
    float4 s0 = make_float4(A0[0] * r0, A0[1] * r0, A0[2] * r0, A0[3] * r0);
    float4 s1 = make_float4(A1[0] * r1, A1[1] * r1, A1[2] * r1, A1[3] * r1);
    *(float4*)(out + (size_t)n * 128 + (gl << 2)) = s0;
    *(float4*)(out + (size_t)n * 128 + 64 + (gl << 2)) = s1;
  }
}

extern "C" void kernel_launch(void* const* d_in, const int* in_sizes, int n_in,
                              void* d_out, int out_size, void* d_ws, size_t ws_size,
                              hipStream_t stream) {
  const float* feat  = (const float*)d_in[0];
  const float* Wsrc  = (const float*)d_in[1];
  const float* bsrc  = (const float*)d_in[2];
  const float* qual  = (const float*)d_in[3];
  const float* Wqual = (const float*)d_in[4];
  const float* bqual = (const float*)d_in[5];
  const float* attn  = (const float*)d_in[6];
  const int* src = (const int*)d_in[7];
  const int* dst = (const int*)d_in[8];
  const int* rt  = (const int*)d_in[9];
  const int* nid = (const int*)d_in[10];
  float* out = (float*)d_out;

  const int N = in_sizes[0] / 64;
  const int E = in_sizes[7];
  const long tabElems = (long)N * 64;
  const int NBKT = (N + 255) / 256;
  const size_t RSLOTS = (size_t)8 * RCAP;

  char* p = (char*)d_ws;
  int* cursor_r = (int*)p;      p += 8 * CTR_STRIDE * 4;
  int* bkt_cur = (int*)p;       p += (size_t)NBKT * CTR_STRIDE * 4;   // contiguous w/ cursor_r
  int2* bc_d = (int2*)p;        p += (size_t)N * 8;
  int* src_r = (int*)p;         p += RSLOTS * 4;
  int* nid_r = (int*)p;         p += RSLOTS * 4;
  uint2* recs = (uint2*)p;      p += (size_t)NBKT * BCAP * 8;
  int* perm_p = (int*)p;        p += (size_t)NBKT * BCAP * 4;
  ushort* Wt = (ushort*)p;      p += 2 * 8 * 64 * 64 * 2;  // 128 KB bf16
  ushort* feat_bf = (ushort*)p; p += (size_t)tabElems * 2;
  ushort* qual_bf = (ushort*)p; p += (size_t)tabElems * 2;
  uint2* rec_sa = (uint2*)p;    p += RSLOTS * 8;
  if ((size_t)(p - (char*)d_ws) > ws_size) return;   // workspace too small: bail visibly

  hipMemsetAsync(cursor_r, 0, (size_t)(8 + NBKT) * CTR_STRIDE * 4, stream);  // relative cursors
  hipMemsetAsync(src_r, 0xFF, RSLOTS * 4, stream);   // -1 sentinels for window padding

  const int p1B = (E + 1023) / 1024;
  const int convB = (int)((2 * tabElems / 8 + 1023) / 1024);
  fused1_k<<<p1B + convB + 4, 1024, 0, stream>>>(src, dst, rt, nid, cursor_r, bkt_cur,
                                                 src_r, nid_r, recs, E, p1B,
                                                 Wsrc, Wqual, Wt,
                                                 feat, qual, feat_bf, qual_bf,
                                                 tabElems, convB);
  const int scoreB = (int)(RSLOTS / 128);
  fused2_k<<<scoreB + NBKT, 256, 0, stream>>>(feat_bf, qual_bf, Wt, bsrc, bqual, attn,
                                              src_r, nid_r, rec_sa, scoreB,
                                              recs, bkt_cur, bc_d, perm_p, N);
  const int nquads = (N + 3) / 4;
  const int aggB = min(2048, (nquads + 3) / 4);
  agg_k<<<aggB, 256, 0, stream>>>(feat_bf, rec_sa, perm_p, bc_d, out, N, nquads);
}